// Round 11
// baseline (403.519 us; speedup 1.0000x reference)
//
#include <hip/hip_runtime.h>

// LIIFParametric3DConv — round 23: cross-wave phase-stagger (zero-register).
// R22 post-mortem: +16 regs (L2 pipelining) spills -> R19 is exactly at the
// 2-wave/SIMD register ceiling; within-wave pipelining is structurally
// unavailable (scheduler pressure-bound -> pipes serialize, Mfma+VALU ~86%
// sum). Only remaining lever: cross-wave anti-phasing. Blocks with bit 9 of
// blockIdx set start L1 at nt=8 and L2 at cg=2 (co-resident pairs are ~512
// apart -> differ in bit 9 -> anti-phased: one wave's VALU tail hides under
// the other's MFMA cluster). L1 = two fully-unrolled uniform branches
// (constant nt -> no runtime a2w indexing, rule #20). L2 rotation is runtime
// (all per-thread arrays constant-indexed). mlp otherwise R19 verbatim;
// prep = R15; conv = R17. Canaries: WRITE_SIZE ~2304KB, VGPR 128, occ ~22,
// absmax <= ~2e-3 (L2 pacc reassociation only).
//
// ws layout (bytes):
//   fhi  @ 0          : 75,497,472
//   flo  @ 75497472   : 75,497,472
//   W1F  @ 150994944  : 32,768
//   W1FL @ 151027712  : 32,768
//   W2F  @ 151060480  : 131,072
//   total 151,191,552

using s16x8 = __attribute__((ext_vector_type(8))) short;
using f32x4 = __attribute__((ext_vector_type(4))) float;
using u32x4 = __attribute__((ext_vector_type(4))) unsigned int;

#define SREV 4.7746482927568600f   // 30/(2*pi)

__device__ __forceinline__ float bf2f(unsigned short u){
  return __uint_as_float(((unsigned)u) << 16);
}
__device__ __forceinline__ short f2bf(float f){
  unsigned b = __float_as_uint(f);
  return (short)((b + 0x7FFFu + ((b >> 16) & 1u)) >> 16);
}
__device__ __forceinline__ float sin_rev(float x){   // sin(2*pi*x)
  float r; asm("v_sin_f32 %0, %1" : "=v"(r) : "v"(x)); return r;
}
__device__ __forceinline__ unsigned cvt_pk_bf16(float lo, float hi){
  unsigned r; asm("v_cvt_pk_bf16_f32 %0, %1, %2" : "=v"(r) : "v"(lo), "v"(hi));
  return r;  // D[15:0]=bf16(lo), D[31:16]=bf16(hi)
}
__device__ __forceinline__ float trunc_hi(float v){
  return __uint_as_float(__float_as_uint(v) & 0xFFFF0000u);
}

// ---------------- prep: fragment-ordered, pre-scaled MLP weights (R15) ------
__global__ __launch_bounds__(256) void prep_kernel(
    const float* __restrict__ W1, const float* __restrict__ W2,
    short* __restrict__ W1F, short* __restrict__ W1FL, short* __restrict__ W2F){
  const int gid = blockIdx.x*256 + threadIdx.x;   // 0..16383
  {
    const int i = gid;
    const int f = i>>9;
    const int r = i&511;
    const int l = r>>3, j = r&7;
    const int nt = f>>1, kk = f&1;
    const int n = nt*16 + (l&15);
    const int k = kk*32 + (l>>4)*8 + j;
    const float w = W1[(size_t)k*256 + n] * SREV;
    const short h = f2bf(w);
    W1F[i]  = h;
    W1FL[i] = f2bf(w - bf2f((unsigned short)h));
  }
  #pragma unroll
  for(int i=gid; i<65536; i+=16384){
    const int f = i>>9;
    const int r = i&511;
    const int l = r>>3, j = r&7;
    const int ks = f&7;
    const int q  = l>>4;
    const int n  = (f>>5)*64 + ((f>>3)&3)*16 + (l&15);
    const int R  = (2*ks + (j>>2))*16 + q*4 + (j&3);
    W2F[i] = f2bf(W2[(size_t)R*256 + n] * SREV);
  }
}

// ---------------- conv3d 2->64 via MFMA im2col GEMM (R17 verbatim) ----------
__global__ __launch_bounds__(256) void conv_kernel(
    const float* __restrict__ xr, const float* __restrict__ xi,
    const float* __restrict__ enc_w, const float* __restrict__ enc_b,
    short* __restrict__ fhi, short* __restrict__ flo)
{
  __shared__ __align__(16) float sm[2560];
  __shared__ __align__(16) int offs[64];
  const int tid  = threadIdx.x;
  const int wave = tid>>6;
  const int lane = tid&63;
  const int q  = lane>>4;
  const int ln = lane&15;

  #pragma unroll
  for(int z=0; z<10; z++) sm[tid + z*256] = 0.f;
  if(tid < 64){
    int off = 2160;                       // sentinel: zeroed pad
    if(tid < 54){
      const int i  = (tid >= 27) ? 1 : 0;
      const int kk = tid - i*27;
      const int dz = kk/9;
      const int rem = kk - dz*9;
      const int dy = rem/3;
      const int dx = rem - dy*3;
      off = ((i*3+dz)*18 + dy)*20 + dx;
    }
    offs[tid] = off;
  }
  __syncthreads();

  const unsigned bi   = blockIdx.x;          // 2304 = 2*32*36
  const unsigned tile = bi % 36u;
  const unsigned t    = (bi/36u) % 32u;
  const unsigned b    = bi / 1152u;
  const int h0 = (int)((tile/6u)*16u);
  const int w0 = (int)((tile%6u)*16u);
  #pragma unroll
  for(int i=0;i<2;i++){
    const float* src = i ? xi : xr;
    #pragma unroll
    for(int dz=0;dz<3;dz++){
      const int tt = (int)t + dz - 1;
      if(tt >= 0 && tt < 32){
        const float* sp = src + (size_t)(b*32u + (unsigned)tt)*9216u;
        float* dp = sm + (i*3+dz)*360;
        for(int e = tid; e < 324; e += 256){
          const int r = e/18, c = e - r*18;
          const int hh = h0-1+r, ww = w0-1+c;
          if(hh>=0 && hh<96 && ww>=0 && ww<96)
            dp[r*20 + c] = sp[hh*96 + ww];
        }
      }
    }
  }
  __syncthreads();

  s16x8 wh[8], wl[8];
  #pragma unroll
  for(int f=0; f<8; f++){
    const int nt = f>>1, ks = f&1;
    const int n  = nt*16 + ln;
    const int k0 = ks*32 + q*8;
    unsigned hp[4], lp[4];
    #pragma unroll
    for(int jp=0; jp<4; jp++){
      const int ka = k0 + jp*2, kb = ka + 1;
      const float v0 = (ka < 54) ? enc_w[n*54 + ka] : 0.f;
      const float v1 = (kb < 54) ? enc_w[n*54 + kb] : 0.f;
      const float a0 = trunc_hi(v0), a1 = trunc_hi(v1);
      hp[jp] = cvt_pk_bf16(a0, a1);
      lp[jp] = cvt_pk_bf16(v0 - a0, v1 - a1);
    }
    u32x4 hv = {hp[0],hp[1],hp[2],hp[3]};
    u32x4 lv = {lp[0],lp[1],lp[2],lp[3]};
    wh[f] = __builtin_bit_cast(s16x8, hv);
    wl[f] = __builtin_bit_cast(s16x8, lv);
  }

  int4 of0a = *(const int4*)(offs + 0*32 + q*8);
  int4 of0b = *(const int4*)(offs + 0*32 + q*8 + 4);
  int4 of1a = *(const int4*)(offs + 1*32 + q*8);
  int4 of1b = *(const int4*)(offs + 1*32 + q*8 + 4);
  int ofv[16] = {of0a.x,of0a.y,of0a.z,of0a.w, of0b.x,of0b.y,of0b.z,of0b.w,
                 of1a.x,of1a.y,of1a.z,of1a.w, of1b.x,of1b.y,of1b.z,of1b.w};
  float4 bq[4];
  #pragma unroll
  for(int nt=0;nt<4;nt++) bq[nt] = *(const float4*)(enc_b + nt*16 + q*4);

  const unsigned rowbase = (b*32u+t)*9216u + (unsigned)(h0*96 + w0);

  #pragma unroll
  for(int rt=0; rt<4; rt++){
    const int R  = wave*4 + rt;
    const int pb = R*20 + ln;
    s16x8 bh[2], bl[2];
    #pragma unroll
    for(int ks=0; ks<2; ks++){
      unsigned hp[4], lp[4];
      #pragma unroll
      for(int jp=0; jp<4; jp++){
        const float v0 = sm[pb + ofv[ks*8 + jp*2 + 0]];
        const float v1 = sm[pb + ofv[ks*8 + jp*2 + 1]];
        const float a0 = trunc_hi(v0), a1 = trunc_hi(v1);
        hp[jp] = cvt_pk_bf16(a0, a1);
        lp[jp] = cvt_pk_bf16(v0 - a0, v1 - a1);
      }
      u32x4 hv = {hp[0],hp[1],hp[2],hp[3]};
      u32x4 lv = {lp[0],lp[1],lp[2],lp[3]};
      bh[ks] = __builtin_bit_cast(s16x8, hv);
      bl[ks] = __builtin_bit_cast(s16x8, lv);
    }
    const size_t pgi = (size_t)(rowbase + (unsigned)(R*96 + ln));
    #pragma unroll
    for(int nt=0; nt<4; nt++){
      f32x4 acc = {0.f,0.f,0.f,0.f};
      #pragma unroll
      for(int ks=0; ks<2; ks++){
        acc = __builtin_amdgcn_mfma_f32_16x16x32_bf16(wh[nt*2+ks], bh[ks], acc, 0,0,0);
        acc = __builtin_amdgcn_mfma_f32_16x16x32_bf16(wh[nt*2+ks], bl[ks], acc, 0,0,0);
        acc = __builtin_amdgcn_mfma_f32_16x16x32_bf16(wl[nt*2+ks], bh[ks], acc, 0,0,0);
      }
      const float v0 = acc[0] + bq[nt].x;
      const float v1 = acc[1] + bq[nt].y;
      const float v2 = acc[2] + bq[nt].z;
      const float v3 = acc[3] + bq[nt].w;
      const float a0 = trunc_hi(v0), a1 = trunc_hi(v1);
      const float a2 = trunc_hi(v2), a3 = trunc_hi(v3);
      const unsigned h01 = cvt_pk_bf16(a0, a1);
      const unsigned h23 = cvt_pk_bf16(a2, a3);
      const unsigned l01 = cvt_pk_bf16(v0 - a0, v1 - a1);
      const unsigned l23 = cvt_pk_bf16(v2 - a2, v3 - a3);
      *(uint2*)(fhi + pgi*64u + (unsigned)(nt*16 + q*4)) = make_uint2(h01, h23);
      *(uint2*)(flo + pgi*64u + (unsigned)(nt*16 + q*4)) = make_uint2(l01, l23);
    }
  }
}

// ---------------- fused SIREN MLP + lerp, RT=4 (R19 + phase-stagger) --------
#define MFMA16(A,B,C) __builtin_amdgcn_mfma_f32_16x16x32_bf16(A,B,C,0,0,0)

// One L1 group, R19 verbatim body. nt must be a compile-time constant at each
// expansion site (a2w write indices constant -> registers, rule #20).
#define L1_GROUP(nt) do{ \
  const int nb_ = (nt)<<4; \
  const s16x8 bf0_ = *(const s16x8*)(W1F  + ((nt)*2+0)*512 + l16); \
  const s16x8 bf1_ = *(const s16x8*)(W1F  + ((nt)*2+1)*512 + l16); \
  const s16x8 bl0_ = *(const s16x8*)(W1FL + ((nt)*2+0)*512 + l16); \
  const s16x8 bl1_ = *(const s16x8*)(W1FL + ((nt)*2+1)*512 + l16); \
  const float4 b1q_ = *(const float4*)(b1 + nb_ + q*4); \
  const float4 w1q_ = *(const float4*)(W1 + 64*256 + nb_ + q*4); \
  f32x4 acc1_[4]; \
  _Pragma("unroll") \
  for(int rt_=0;rt_<4;rt_++){ const f32x4 zv_ = {0.f,0.f,0.f,0.f}; acc1_[rt_]=zv_; } \
  _Pragma("unroll") for(int rt_=0;rt_<4;rt_++) acc1_[rt_] = MFMA16(bf0_, ahi[rt_][0], acc1_[rt_]); \
  _Pragma("unroll") for(int rt_=0;rt_<4;rt_++) acc1_[rt_] = MFMA16(bf1_, ahi[rt_][1], acc1_[rt_]); \
  _Pragma("unroll") for(int rt_=0;rt_<4;rt_++) acc1_[rt_] = MFMA16(bf0_, alo[rt_][0], acc1_[rt_]); \
  _Pragma("unroll") for(int rt_=0;rt_<4;rt_++) acc1_[rt_] = MFMA16(bf1_, alo[rt_][1], acc1_[rt_]); \
  _Pragma("unroll") for(int rt_=0;rt_<4;rt_++) acc1_[rt_] = MFMA16(bl0_, ahi[rt_][0], acc1_[rt_]); \
  _Pragma("unroll") for(int rt_=0;rt_<4;rt_++) acc1_[rt_] = MFMA16(bl1_, ahi[rt_][1], acc1_[rt_]); \
  _Pragma("unroll") \
  for(int rt_=0;rt_<4;rt_++){ \
    const float tcr_ = tcv[rt_]; \
    const float s0_ = sin_rev(fmaf(SREV, fmaf(tcr_, w1q_.x, b1q_.x), acc1_[rt_][0])); \
    const float s1_ = sin_rev(fmaf(SREV, fmaf(tcr_, w1q_.y, b1q_.y), acc1_[rt_][1])); \
    const float s2_ = sin_rev(fmaf(SREV, fmaf(tcr_, w1q_.z, b1q_.z), acc1_[rt_][2])); \
    const float s3_ = sin_rev(fmaf(SREV, fmaf(tcr_, w1q_.w, b1q_.w), acc1_[rt_][3])); \
    a2w[rt_][(nt)>>1][((nt)&1)*2+0] = cvt_pk_bf16(s0_,s1_); \
    a2w[rt_][(nt)>>1][((nt)&1)*2+1] = cvt_pk_bf16(s2_,s3_); \
  } }while(0)

__global__ __launch_bounds__(256, 2) void mlp_kernel(
  const float* __restrict__ tcoord,
  const short* __restrict__ fhi, const short* __restrict__ flo,
  const short* __restrict__ W1F, const short* __restrict__ W1FL,
  const float* __restrict__ W1,  const float* __restrict__ b1,
  const short* __restrict__ W2F, const float* __restrict__ b2,
  const float* __restrict__ W3,  const float* __restrict__ b3,
  float* __restrict__ out)
{
  const int tid  = threadIdx.x;
  const int wave = tid>>6;
  const int lane = tid&63;
  const int q  = lane>>4;   // quad
  const int ln = lane&15;
  const int l16 = lane*8;
  const unsigned evbase = blockIdx.x*256u + (unsigned)wave*64u;
  // phase-stagger select: co-resident blocks are ~512 apart -> bit 9 differs
  const int rot = (int)((blockIdx.x>>9)&1u);

  // ---- per-lane meta for eval (evbase + lane) ----
  const unsigned ev = evbase + (unsigned)lane;
  const unsigned pt = ev>>1;
  const unsigned fc = ev&1u;
  const unsigned wq = pt%96u;
  const unsigned hq = (pt/96u)%96u;
  const unsigned jq = (pt/9216u)%32u;
  const unsigned bq = pt/294912u;
  float tc = tcoord[bq*32u+jq];
  tc = fminf(fmaxf(tc, -1.0f), 1.0f - 1e-6f);
  const float dstep = 2.0f/31.0f;
  const int ti = (int)floorf((tc+1.0f)/dstep);
  const unsigned trow = (unsigned)ti + fc;       // <= 31
  const unsigned rowoff = (bq*32u+trow)*9216u + hq*96u + wq;

  // per row-tile rt: feature row offset + own-eval tc
  float tcv[4];
  s16x8 ahi[4][2], alo[4][2];
  #pragma unroll
  for(int rt=0;rt<4;rt++){
    const unsigned offr = __shfl(rowoff, rt*16 + ln, 64);
    tcv[rt] = __shfl(tc, rt*16 + ln, 64);
    const size_t o = (size_t)offr*64u + (size_t)(q*8);
    ahi[rt][0] = *(const s16x8*)(fhi+o);  ahi[rt][1] = *(const s16x8*)(fhi+o+32);
    alo[rt][0] = *(const s16x8*)(flo+o);  alo[rt][1] = *(const s16x8*)(flo+o+32);
  }

  // ---- layer 1 (swapped), phase-staggered group order ----
  u32x4 a2w[4][8];
  if(rot == 0){
    #pragma unroll
    for(int i=0;i<16;i++){ L1_GROUP(i); }
  } else {
    #pragma unroll
    for(int i=0;i<16;i++){ L1_GROUP((i+8)&15); }
  }

  // ---- layer 2 (+3 folded): ks-innermost, 4 independent rt-chains,
  //      cg order rotated by phase (runtime cg: per-thread arrays all
  //      constant-indexed, rule #20 safe) ----
  float pacc[4][4];
  #pragma unroll
  for(int rt=0;rt<4;rt++)
    #pragma unroll
    for(int rr=0;rr<4;rr++) pacc[rt][rr]=0.f;

  #pragma unroll 1
  for(int c=0; c<4; c++){
    const int cg = (c + rot*2) & 3;
    #pragma unroll
    for(int nt=0;nt<4;nt++){
      f32x4 acc2[4];
      const f32x4 zv = {0.f,0.f,0.f,0.f};
      #pragma unroll
      for(int rt=0;rt<4;rt++) acc2[rt] = zv;
      #pragma unroll
      for(int ks=0; ks<8; ks++){
        const s16x8 bfr = *(const s16x8*)(W2F + (((cg*4+nt)*8+ks)*512) + l16);
        #pragma unroll
        for(int rt=0;rt<4;rt++){
          const s16x8 a2 = __builtin_bit_cast(s16x8, a2w[rt][ks]);
          acc2[rt] = __builtin_amdgcn_mfma_f32_16x16x32_bf16(a2, bfr, acc2[rt], 0,0,0);
        }
      }
      const int n = cg*64 + nt*16 + ln;
      const float sb2 = SREV * b2[n];
      const float w3v = W3[n];
      #pragma unroll
      for(int rt=0;rt<4;rt++)
        #pragma unroll
        for(int rr=0;rr<4;rr++){
          const float h2 = sin_rev(acc2[rt][rr] + sb2);
          pacc[rt][rr] += h2*w3v;
        }
    }
  }

  // reduce over the 16 n-lanes (xor within ln bits keeps q fixed)
  #pragma unroll
  for(int rt=0;rt<4;rt++)
    #pragma unroll
    for(int rr=0;rr<4;rr++){
      float v = pacc[rt][rr];
      v += __shfl_xor(v, 1, 64);
      v += __shfl_xor(v, 2, 64);
      v += __shfl_xor(v, 4, 64);
      v += __shfl_xor(v, 8, 64);
      pacc[rt][rr] = v;
    }

  // ---- fused lerp: rows (2s, 2s+1) = (floor, ceil) of one pixel ----
  float tcp_[4][2];
  #pragma unroll
  for(int rt=0;rt<4;rt++)
    #pragma unroll
    for(int s=0;s<2;s++)
      tcp_[rt][s] = __shfl(tc, rt*16 + q*4 + 2*s, 64);

  if(ln==0){
    const float b3v = b3[0];
    #pragma unroll
    for(int rt=0;rt<4;rt++){
      #pragma unroll
      for(int s=0;s<2;s++){
        const int m0 = rt*16 + q*4 + 2*s;
        const float tcp = tcp_[rt][s];
        const int tip = (int)floorf((tcp+1.0f)/dstep);
        const float fci = (float)((double)tip*(2.0/31.0) - 1.0);
        const float tau = (tcp - fci)/dstep;
        const unsigned px = (evbase + (unsigned)m0)>>1;
        out[px] = pacc[rt][2*s]*(1.0f-tau) + pacc[rt][2*s+1]*tau + b3v;
      }
    }
  }
}

extern "C" void kernel_launch(void* const* d_in, const int* in_sizes, int n_in,
                              void* d_out, int out_size, void* d_ws, size_t ws_size,
                              hipStream_t stream){
  const float* xr     = (const float*)d_in[0];
  const float* xi     = (const float*)d_in[1];
  const float* tcoord = (const float*)d_in[2];
  const float* enc_w  = (const float*)d_in[3];
  const float* enc_b  = (const float*)d_in[4];
  const float* W1     = (const float*)d_in[5];
  const float* b1     = (const float*)d_in[6];
  const float* W2     = (const float*)d_in[7];
  const float* b2     = (const float*)d_in[8];
  const float* W3     = (const float*)d_in[9];
  const float* b3     = (const float*)d_in[10];

  char* ws = (char*)d_ws;
  short* fhi  = (short*)(ws);
  short* flo  = (short*)(ws + 75497472);
  short* W1F  = (short*)(ws + 150994944);
  short* W1FL = (short*)(ws + 151027712);
  short* W2F  = (short*)(ws + 151060480);
  float* out  = (float*)d_out;

  hipLaunchKernelGGL(prep_kernel, dim3(64),   dim3(256), 0, stream, W1, W2, W1F, W1FL, W2F);
  hipLaunchKernelGGL(conv_kernel, dim3(2304), dim3(256), 0, stream, xr, xi, enc_w, enc_b, fhi, flo);
  hipLaunchKernelGGL(mlp_kernel,  dim3(4608), dim3(256), 0, stream, tcoord, fhi, flo,
                     W1F, W1FL, W1, b1, W2F, b2, W3, b3, out);
}

// Round 13
// 369.273 us; speedup vs baseline: 1.0927x; 1.0927x over previous
//
#include <hip/hip_runtime.h>

// LIIFParametric3DConv — round 25: conv store coalescing (LDS transpose flush).
// R24 post-mortem: C-init folding CONVICTED as R21's bug (n=2 fail with, n=2
// pass without) — permanently quarantined; mechanism sub-source (MFMA SrcC
// init hazard suspected). mlp reverted to R19 verbatim (282us champion).
// This round attacks the 113us total-mlp gap: R17-conv's uint2 stores are
// 128B lane-strided -> 64 lines/instr, ~19M line-transactions (~30us TA).
// Fix: per-wave LDS tile (short[2][16][72], 16B-aligned rows) collects each
// rt-row's 16px x 64ch, then lane-contiguous dwordx4 flush (32 lines/rt vs
// 512). Conv values bit-identical; wave-private tile -> no barriers.
// Canaries: absmax 0.001953125 exactly; mlp rows unchanged; WRITE 2304.
//
// ws layout (bytes):
//   fhi  @ 0          : 75,497,472
//   flo  @ 75497472   : 75,497,472
//   W1F  @ 150994944  : 32,768
//   W1FL @ 151027712  : 32,768
//   W2F  @ 151060480  : 131,072
//   total 151,191,552

using s16x8 = __attribute__((ext_vector_type(8))) short;
using f32x4 = __attribute__((ext_vector_type(4))) float;
using u32x4 = __attribute__((ext_vector_type(4))) unsigned int;

#define SREV 4.7746482927568600f   // 30/(2*pi)

__device__ __forceinline__ float bf2f(unsigned short u){
  return __uint_as_float(((unsigned)u) << 16);
}
__device__ __forceinline__ short f2bf(float f){
  unsigned b = __float_as_uint(f);
  return (short)((b + 0x7FFFu + ((b >> 16) & 1u)) >> 16);
}
__device__ __forceinline__ float sin_rev(float x){   // sin(2*pi*x)
  float r; asm("v_sin_f32 %0, %1" : "=v"(r) : "v"(x)); return r;
}
__device__ __forceinline__ unsigned cvt_pk_bf16(float lo, float hi){
  unsigned r; asm("v_cvt_pk_bf16_f32 %0, %1, %2" : "=v"(r) : "v"(lo), "v"(hi));
  return r;  // D[15:0]=bf16(lo), D[31:16]=bf16(hi)
}
__device__ __forceinline__ float trunc_hi(float v){
  return __uint_as_float(__float_as_uint(v) & 0xFFFF0000u);
}

// ---------------- prep: fragment-ordered, pre-scaled MLP weights (R15) ------
__global__ __launch_bounds__(256) void prep_kernel(
    const float* __restrict__ W1, const float* __restrict__ W2,
    short* __restrict__ W1F, short* __restrict__ W1FL, short* __restrict__ W2F){
  const int gid = blockIdx.x*256 + threadIdx.x;   // 0..16383
  {
    const int i = gid;
    const int f = i>>9;
    const int r = i&511;
    const int l = r>>3, j = r&7;
    const int nt = f>>1, kk = f&1;
    const int n = nt*16 + (l&15);
    const int k = kk*32 + (l>>4)*8 + j;
    const float w = W1[(size_t)k*256 + n] * SREV;
    const short h = f2bf(w);
    W1F[i]  = h;
    W1FL[i] = f2bf(w - bf2f((unsigned short)h));
  }
  #pragma unroll
  for(int i=gid; i<65536; i+=16384){
    const int f = i>>9;
    const int r = i&511;
    const int l = r>>3, j = r&7;
    const int ks = f&7;
    const int q  = l>>4;
    const int n  = (f>>5)*64 + ((f>>3)&3)*16 + (l&15);
    const int R  = (2*ks + (j>>2))*16 + q*4 + (j&3);
    W2F[i] = f2bf(W2[(size_t)R*256 + n] * SREV);
  }
}

// ---------------- conv3d 2->64 via MFMA im2col GEMM + coalesced flush -------
__global__ __launch_bounds__(256) void conv_kernel(
    const float* __restrict__ xr, const float* __restrict__ xi,
    const float* __restrict__ enc_w, const float* __restrict__ enc_b,
    short* __restrict__ fhi, short* __restrict__ flo)
{
  __shared__ __align__(16) float sm[2560];
  __shared__ __align__(16) int offs[64];
  // per-wave transpose tile: [wave][hi/lo][px 0..15][ch 0..63 pad 72]
  // row stride 144B (16B-aligned); wave-private -> no barriers needed.
  __shared__ __align__(16) short wtile[4][2][16][72];
  const int tid  = threadIdx.x;
  const int wave = tid>>6;
  const int lane = tid&63;
  const int q  = lane>>4;
  const int ln = lane&15;

  #pragma unroll
  for(int z=0; z<10; z++) sm[tid + z*256] = 0.f;
  if(tid < 64){
    int off = 2160;                       // sentinel: zeroed pad
    if(tid < 54){
      const int i  = (tid >= 27) ? 1 : 0;
      const int kk = tid - i*27;
      const int dz = kk/9;
      const int rem = kk - dz*9;
      const int dy = rem/3;
      const int dx = rem - dy*3;
      off = ((i*3+dz)*18 + dy)*20 + dx;
    }
    offs[tid] = off;
  }
  __syncthreads();

  const unsigned bi   = blockIdx.x;          // 2304 = 2*32*36
  const unsigned tile = bi % 36u;
  const unsigned t    = (bi/36u) % 32u;
  const unsigned b    = bi / 1152u;
  const int h0 = (int)((tile/6u)*16u);
  const int w0 = (int)((tile%6u)*16u);
  #pragma unroll
  for(int i=0;i<2;i++){
    const float* src = i ? xi : xr;
    #pragma unroll
    for(int dz=0;dz<3;dz++){
      const int tt = (int)t + dz - 1;
      if(tt >= 0 && tt < 32){
        const float* sp = src + (size_t)(b*32u + (unsigned)tt)*9216u;
        float* dp = sm + (i*3+dz)*360;
        for(int e = tid; e < 324; e += 256){
          const int r = e/18, c = e - r*18;
          const int hh = h0-1+r, ww = w0-1+c;
          if(hh>=0 && hh<96 && ww>=0 && ww<96)
            dp[r*20 + c] = sp[hh*96 + ww];
        }
      }
    }
  }
  __syncthreads();

  s16x8 wh[8], wl[8];
  #pragma unroll
  for(int f=0; f<8; f++){
    const int nt = f>>1, ks = f&1;
    const int n  = nt*16 + ln;
    const int k0 = ks*32 + q*8;
    unsigned hp[4], lp[4];
    #pragma unroll
    for(int jp=0; jp<4; jp++){
      const int ka = k0 + jp*2, kb = ka + 1;
      const float v0 = (ka < 54) ? enc_w[n*54 + ka] : 0.f;
      const float v1 = (kb < 54) ? enc_w[n*54 + kb] : 0.f;
      const float a0 = trunc_hi(v0), a1 = trunc_hi(v1);
      hp[jp] = cvt_pk_bf16(a0, a1);
      lp[jp] = cvt_pk_bf16(v0 - a0, v1 - a1);
    }
    u32x4 hv = {hp[0],hp[1],hp[2],hp[3]};
    u32x4 lv = {lp[0],lp[1],lp[2],lp[3]};
    wh[f] = __builtin_bit_cast(s16x8, hv);
    wl[f] = __builtin_bit_cast(s16x8, lv);
  }

  int4 of0a = *(const int4*)(offs + 0*32 + q*8);
  int4 of0b = *(const int4*)(offs + 0*32 + q*8 + 4);
  int4 of1a = *(const int4*)(offs + 1*32 + q*8);
  int4 of1b = *(const int4*)(offs + 1*32 + q*8 + 4);
  int ofv[16] = {of0a.x,of0a.y,of0a.z,of0a.w, of0b.x,of0b.y,of0b.z,of0b.w,
                 of1a.x,of1a.y,of1a.z,of1a.w, of1b.x,of1b.y,of1b.z,of1b.w};
  float4 bq[4];
  #pragma unroll
  for(int nt=0;nt<4;nt++) bq[nt] = *(const float4*)(enc_b + nt*16 + q*4);

  const unsigned rowbase = (b*32u+t)*9216u + (unsigned)(h0*96 + w0);

  #pragma unroll
  for(int rt=0; rt<4; rt++){
    const int R  = wave*4 + rt;
    const int pb = R*20 + ln;
    s16x8 bh[2], bl[2];
    #pragma unroll
    for(int ks=0; ks<2; ks++){
      unsigned hp[4], lp[4];
      #pragma unroll
      for(int jp=0; jp<4; jp++){
        const float v0 = sm[pb + ofv[ks*8 + jp*2 + 0]];
        const float v1 = sm[pb + ofv[ks*8 + jp*2 + 1]];
        const float a0 = trunc_hi(v0), a1 = trunc_hi(v1);
        hp[jp] = cvt_pk_bf16(a0, a1);
        lp[jp] = cvt_pk_bf16(v0 - a0, v1 - a1);
      }
      u32x4 hv = {hp[0],hp[1],hp[2],hp[3]};
      u32x4 lv = {lp[0],lp[1],lp[2],lp[3]};
      bh[ks] = __builtin_bit_cast(s16x8, hv);
      bl[ks] = __builtin_bit_cast(s16x8, lv);
    }
    #pragma unroll
    for(int nt=0; nt<4; nt++){
      f32x4 acc = {0.f,0.f,0.f,0.f};
      #pragma unroll
      for(int ks=0; ks<2; ks++){
        acc = __builtin_amdgcn_mfma_f32_16x16x32_bf16(wh[nt*2+ks], bh[ks], acc, 0,0,0);
        acc = __builtin_amdgcn_mfma_f32_16x16x32_bf16(wh[nt*2+ks], bl[ks], acc, 0,0,0);
        acc = __builtin_amdgcn_mfma_f32_16x16x32_bf16(wl[nt*2+ks], bh[ks], acc, 0,0,0);
      }
      const float v0 = acc[0] + bq[nt].x;
      const float v1 = acc[1] + bq[nt].y;
      const float v2 = acc[2] + bq[nt].z;
      const float v3 = acc[3] + bq[nt].w;
      const float a0 = trunc_hi(v0), a1 = trunc_hi(v1);
      const float a2 = trunc_hi(v2), a3 = trunc_hi(v3);
      const unsigned h01 = cvt_pk_bf16(a0, a1);
      const unsigned h23 = cvt_pk_bf16(a2, a3);
      const unsigned l01 = cvt_pk_bf16(v0 - a0, v1 - a1);
      const unsigned l23 = cvt_pk_bf16(v2 - a2, v3 - a3);
      // stage into per-wave LDS tile (was: 128B-strided uint2 global stores)
      *(uint2*)&wtile[wave][0][ln][nt*16 + q*4] = make_uint2(h01, h23);
      *(uint2*)&wtile[wave][1][ln][nt*16 + q*4] = make_uint2(l01, l23);
    }
    // coalesced flush: row R's 16px x 64ch = 2KB contiguous per buffer.
    // lane chunk c covers shorts [c*8, c*8+8) -> px=c>>3, ch8=(c&7)*8.
    const size_t gbase = (size_t)(rowbase + (unsigned)(R*96)) * 64u;
    #pragma unroll
    for(int it=0; it<2; it++){
      const int c   = lane + it*64;     // 0..127
      const int px  = c >> 3;
      const int ch8 = (c & 7) * 8;
      *(uint4*)(fhi + gbase + (size_t)c*8u) = *(const uint4*)&wtile[wave][0][px][ch8];
      *(uint4*)(flo + gbase + (size_t)c*8u) = *(const uint4*)&wtile[wave][1][px][ch8];
    }
  }
}

// ---------------- fused SIREN MLP + lerp, RT=4 (R19 verbatim, 282us) --------
__global__ __launch_bounds__(256, 2) void mlp_kernel(
  const float* __restrict__ tcoord,
  const short* __restrict__ fhi, const short* __restrict__ flo,
  const short* __restrict__ W1F, const short* __restrict__ W1FL,
  const float* __restrict__ W1,  const float* __restrict__ b1,
  const short* __restrict__ W2F, const float* __restrict__ b2,
  const float* __restrict__ W3,  const float* __restrict__ b3,
  float* __restrict__ out)
{
  const int tid  = threadIdx.x;
  const int wave = tid>>6;
  const int lane = tid&63;
  const int q  = lane>>4;   // quad
  const int ln = lane&15;
  const int l16 = lane*8;
  const unsigned evbase = blockIdx.x*256u + (unsigned)wave*64u;

  // ---- per-lane meta for eval (evbase + lane) ----
  const unsigned ev = evbase + (unsigned)lane;
  const unsigned pt = ev>>1;
  const unsigned fc = ev&1u;
  const unsigned wq = pt%96u;
  const unsigned hq = (pt/96u)%96u;
  const unsigned jq = (pt/9216u)%32u;
  const unsigned bq = pt/294912u;
  float tc = tcoord[bq*32u+jq];
  tc = fminf(fmaxf(tc, -1.0f), 1.0f - 1e-6f);
  const float dstep = 2.0f/31.0f;
  const int ti = (int)floorf((tc+1.0f)/dstep);
  const unsigned trow = (unsigned)ti + fc;       // <= 31
  const unsigned rowoff = (bq*32u+trow)*9216u + hq*96u + wq;

  // per row-tile rt: feature row offset + own-eval tc
  float tcv[4];
  s16x8 ahi[4][2], alo[4][2];
  #pragma unroll
  for(int rt=0;rt<4;rt++){
    const unsigned offr = __shfl(rowoff, rt*16 + ln, 64);
    tcv[rt] = __shfl(tc, rt*16 + ln, 64);
    const size_t o = (size_t)offr*64u + (size_t)(q*8);
    ahi[rt][0] = *(const s16x8*)(fhi+o);  ahi[rt][1] = *(const s16x8*)(fhi+o+32);
    alo[rt][0] = *(const s16x8*)(flo+o);  alo[rt][1] = *(const s16x8*)(flo+o+32);
  }

  // ---- layer 1 (swapped): 6 passes x 4 independent rt chains ----
  u32x4 a2w[4][8];
  #pragma unroll
  for(int nt=0; nt<16; nt++){
    const int nb = nt<<4;
    const s16x8 bf0 = *(const s16x8*)(W1F  + (nt*2+0)*512 + l16);
    const s16x8 bf1 = *(const s16x8*)(W1F  + (nt*2+1)*512 + l16);
    const s16x8 bl0 = *(const s16x8*)(W1FL + (nt*2+0)*512 + l16);
    const s16x8 bl1 = *(const s16x8*)(W1FL + (nt*2+1)*512 + l16);
    const float4 b1q = *(const float4*)(b1 + nb + q*4);           // b1[n] (raw)
    const float4 w1q = *(const float4*)(W1 + 64*256 + nb + q*4);  // W1[64][n] (raw)
    f32x4 acc1[4];
    #pragma unroll
    for(int rt=0;rt<4;rt++){ const f32x4 zv = {0.f,0.f,0.f,0.f}; acc1[rt]=zv; }
    #pragma unroll
    for(int rt=0;rt<4;rt++)
      acc1[rt] = __builtin_amdgcn_mfma_f32_16x16x32_bf16(bf0, ahi[rt][0], acc1[rt], 0,0,0);
    #pragma unroll
    for(int rt=0;rt<4;rt++)
      acc1[rt] = __builtin_amdgcn_mfma_f32_16x16x32_bf16(bf1, ahi[rt][1], acc1[rt], 0,0,0);
    #pragma unroll
    for(int rt=0;rt<4;rt++)
      acc1[rt] = __builtin_amdgcn_mfma_f32_16x16x32_bf16(bf0, alo[rt][0], acc1[rt], 0,0,0);
    #pragma unroll
    for(int rt=0;rt<4;rt++)
      acc1[rt] = __builtin_amdgcn_mfma_f32_16x16x32_bf16(bf1, alo[rt][1], acc1[rt], 0,0,0);
    #pragma unroll
    for(int rt=0;rt<4;rt++)
      acc1[rt] = __builtin_amdgcn_mfma_f32_16x16x32_bf16(bl0, ahi[rt][0], acc1[rt], 0,0,0);
    #pragma unroll
    for(int rt=0;rt<4;rt++)
      acc1[rt] = __builtin_amdgcn_mfma_f32_16x16x32_bf16(bl1, ahi[rt][1], acc1[rt], 0,0,0);
    #pragma unroll
    for(int rt=0;rt<4;rt++){
      const float tcr = tcv[rt];
      const float s0 = sin_rev(fmaf(SREV, fmaf(tcr, w1q.x, b1q.x), acc1[rt][0]));
      const float s1 = sin_rev(fmaf(SREV, fmaf(tcr, w1q.y, b1q.y), acc1[rt][1]));
      const float s2 = sin_rev(fmaf(SREV, fmaf(tcr, w1q.z, b1q.z), acc1[rt][2]));
      const float s3 = sin_rev(fmaf(SREV, fmaf(tcr, w1q.w, b1q.w), acc1[rt][3]));
      a2w[rt][nt>>1][(nt&1)*2+0] = cvt_pk_bf16(s0,s1);
      a2w[rt][nt>>1][(nt&1)*2+1] = cvt_pk_bf16(s2,s3);
    }
  }

  // ---- layer 2 (+3 folded): ks-innermost, 4 independent rt-chains ----
  float pacc[4][4];
  #pragma unroll
  for(int rt=0;rt<4;rt++)
    #pragma unroll
    for(int rr=0;rr<4;rr++) pacc[rt][rr]=0.f;

  #pragma unroll 1
  for(int cg=0; cg<4; cg++){
    #pragma unroll
    for(int nt=0;nt<4;nt++){
      f32x4 acc2[4];
      const f32x4 zv = {0.f,0.f,0.f,0.f};
      #pragma unroll
      for(int rt=0;rt<4;rt++) acc2[rt] = zv;
      #pragma unroll
      for(int ks=0; ks<8; ks++){
        const s16x8 bfr = *(const s16x8*)(W2F + (((cg*4+nt)*8+ks)*512) + l16);
        #pragma unroll
        for(int rt=0;rt<4;rt++){
          const s16x8 a2 = __builtin_bit_cast(s16x8, a2w[rt][ks]);
          acc2[rt] = __builtin_amdgcn_mfma_f32_16x16x32_bf16(a2, bfr, acc2[rt], 0,0,0);
        }
      }
      const int n = cg*64 + nt*16 + ln;
      const float sb2 = SREV * b2[n];
      const float w3v = W3[n];
      #pragma unroll
      for(int rt=0;rt<4;rt++)
        #pragma unroll
        for(int rr=0;rr<4;rr++){
          const float h2 = sin_rev(acc2[rt][rr] + sb2);
          pacc[rt][rr] += h2*w3v;
        }
    }
  }

  // reduce over the 16 n-lanes (xor within ln bits keeps q fixed)
  #pragma unroll
  for(int rt=0;rt<4;rt++)
    #pragma unroll
    for(int rr=0;rr<4;rr++){
      float v = pacc[rt][rr];
      v += __shfl_xor(v, 1, 64);
      v += __shfl_xor(v, 2, 64);
      v += __shfl_xor(v, 4, 64);
      v += __shfl_xor(v, 8, 64);
      pacc[rt][rr] = v;
    }

  // ---- fused lerp: rows (2s, 2s+1) = (floor, ceil) of one pixel ----
  float tcp_[4][2];
  #pragma unroll
  for(int rt=0;rt<4;rt++)
    #pragma unroll
    for(int s=0;s<2;s++)
      tcp_[rt][s] = __shfl(tc, rt*16 + q*4 + 2*s, 64);

  if(ln==0){
    const float b3v = b3[0];
    #pragma unroll
    for(int rt=0;rt<4;rt++){
      #pragma unroll
      for(int s=0;s<2;s++){
        const int m0 = rt*16 + q*4 + 2*s;
        const float tcp = tcp_[rt][s];
        const int tip = (int)floorf((tcp+1.0f)/dstep);
        const float fci = (float)((double)tip*(2.0/31.0) - 1.0);
        const float tau = (tcp - fci)/dstep;
        const unsigned px = (evbase + (unsigned)m0)>>1;
        out[px] = pacc[rt][2*s]*(1.0f-tau) + pacc[rt][2*s+1]*tau + b3v;
      }
    }
  }
}

extern "C" void kernel_launch(void* const* d_in, const int* in_sizes, int n_in,
                              void* d_out, int out_size, void* d_ws, size_t ws_size,
                              hipStream_t stream){
  const float* xr     = (const float*)d_in[0];
  const float* xi     = (const float*)d_in[1];
  const float* tcoord = (const float*)d_in[2];
  const float* enc_w  = (const float*)d_in[3];
  const float* enc_b  = (const float*)d_in[4];
  const float* W1     = (const float*)d_in[5];
  const float* b1     = (const float*)d_in[6];
  const float* W2     = (const float*)d_in[7];
  const float* b2     = (const float*)d_in[8];
  const float* W3     = (const float*)d_in[9];
  const float* b3     = (const float*)d_in[10];

  char* ws = (char*)d_ws;
  short* fhi  = (short*)(ws);
  short* flo  = (short*)(ws + 75497472);
  short* W1F  = (short*)(ws + 150994944);
  short* W1FL = (short*)(ws + 151027712);
  short* W2F  = (short*)(ws + 151060480);
  float* out  = (float*)d_out;

  hipLaunchKernelGGL(prep_kernel, dim3(64),   dim3(256), 0, stream, W1, W2, W1F, W1FL, W2F);
  hipLaunchKernelGGL(conv_kernel, dim3(2304), dim3(256), 0, stream, xr, xi, enc_w, enc_b, fhi, flo);
  hipLaunchKernelGGL(mlp_kernel,  dim3(4608), dim3(256), 0, stream, tcoord, fhi, flo,
                     W1F, W1FL, W1, b1, W2F, b2, W3, b3, out);
}